// Round 4
// baseline (173.584 us; speedup 1.0000x reference)
//
#include <hip/hip_runtime.h>

// out[p*B + b, o] = x[b, perm[indices[p]][o]]  where T[i] = eye(D)[perm[i]]
// (T[p][o][d] == 1 iff d == perm[p][o])
//
// Two phases:
//  1) extract the combined permutation table (8 x 1024 ints, 32 KB in d_ws)
//  2) pure gather: LDS-stage 4 x-rows per block, indices held in registers,
//     16 KB contiguous nontemporal stores per p-slot.

#define NUM_P 8
#define BATCH 4096
#define DIM   1024
#define TB    4      // batch rows per gather block

// native clang vector types: __builtin_nontemporal_* requires these
// (HIP's float4/int4 are classes and are rejected).
typedef float fx4 __attribute__((ext_vector_type(4)));
typedef int   ix4 __attribute__((ext_vector_type(4)));

// One wave (64 lanes) per output row (p, o): scan T[indices[p]][o][:] for the 1.0.
__global__ __launch_bounds__(256) void extract_perm_kernel(
        const float* __restrict__ T,
        const int* __restrict__ indices,
        int* __restrict__ perm) {
    int wave = (blockIdx.x << 2) | (threadIdx.x >> 6);  // 4 waves/block
    int lane = threadIdx.x & 63;
    int p = wave >> 10;          // output slot 0..7
    int o = wave & 1023;         // row within the permutation matrix
    int src = indices[p];        // which T block feeds output slot p
    const fx4* row = (const fx4*)(T + ((size_t)src * DIM + o) * DIM);

    int cand = 0;                // exactly one element of the row is 1.0
    #pragma unroll
    for (int k = 0; k < 4; ++k) {
        fx4 v = __builtin_nontemporal_load(row + lane + k * 64);  // coalesced 16B/lane
        int d0 = (lane + k * 64) * 4;
        if (v.x > 0.5f) cand = d0;
        if (v.y > 0.5f) cand = d0 + 1;
        if (v.z > 0.5f) cand = d0 + 2;
        if (v.w > 0.5f) cand = d0 + 3;
    }
    // wave-wide max reduce (losers hold 0, winner holds the index)
    #pragma unroll
    for (int off = 32; off >= 1; off >>= 1)
        cand = max(cand, __shfl_xor(cand, off));
    if (lane == 0) perm[p * DIM + o] = cand;
}

// One block per TB batch rows: indices in registers, x rows in LDS,
// coalesced float4 nontemporal stores (16 KB contiguous per p-slot).
__global__ __launch_bounds__(256) void permute_gather_kernel(
        const float* __restrict__ x,
        const int* __restrict__ perm,
        float* __restrict__ out) {
    __shared__ float xs[TB][DIM];
    const int b0 = blockIdx.x * TB;
    const int tid = threadIdx.x;

    // all 8 index quads -> registers (32 VGPRs), loaded once, L1/L2-hot
    ix4 idx[NUM_P];
    #pragma unroll
    for (int p = 0; p < NUM_P; ++p)
        idx[p] = ((const ix4*)(perm + p * DIM))[tid];

    // stage TB rows of x (coalesced float4: 16 KB total)
    #pragma unroll
    for (int r = 0; r < TB; ++r)
        ((fx4*)xs[r])[tid] = ((const fx4*)(x + (size_t)(b0 + r) * DIM))[tid];
    __syncthreads();

    #pragma unroll
    for (int p = 0; p < NUM_P; ++p) {
        #pragma unroll
        for (int r = 0; r < TB; ++r) {
            fx4 v;
            v.x = xs[r][idx[p].x];
            v.y = xs[r][idx[p].y];
            v.z = xs[r][idx[p].z];
            v.w = xs[r][idx[p].w];
            __builtin_nontemporal_store(
                v, (fx4*)(out + ((size_t)(p * BATCH + b0 + r)) * DIM) + tid);
        }
    }
}

extern "C" void kernel_launch(void* const* d_in, const int* in_sizes, int n_in,
                              void* d_out, int out_size, void* d_ws, size_t ws_size,
                              hipStream_t stream) {
    const float* x       = (const float*)d_in[0];
    const float* T       = (const float*)d_in[1];
    const int*   indices = (const int*)d_in[2];
    float*       out     = (float*)d_out;
    int*         perm    = (int*)d_ws;   // 8*1024*4 = 32 KB scratch

    // 8192 rows, one wave each, 4 waves per 256-thread block -> 2048 blocks
    extract_perm_kernel<<<(NUM_P * DIM) / 4, 256, 0, stream>>>(T, indices, perm);
    // 4096/TB = 1024 blocks, each writes 8 x 16 KB contiguous chunks
    permute_gather_kernel<<<BATCH / TB, 256, 0, stream>>>(x, perm, out);
}

// Round 5
// 172.909 us; speedup vs baseline: 1.0039x; 1.0039x over previous
//
#include <hip/hip_runtime.h>

// out[p*B + b, o] = x[b, perm[indices[p]][o]]  where T[i] = eye(D)[perm[i]]
// (T[p][o][d] == 1 iff d == perm[p][o])
//
// Two phases:
//  1) extract the combined permutation table (8 x 1024 ints, 32 KB in d_ws)
//     with wave-uniform early-exit (expected 2.5/4 chunks of each row read)
//  2) pure gather: LDS-stage 4 x-rows per block, indices held in registers,
//     16 KB contiguous nontemporal stores per p-slot.

#define NUM_P 8
#define BATCH 4096
#define DIM   1024
#define TB    4      // batch rows per gather block

// native clang vector types: __builtin_nontemporal_* requires these
// (HIP's float4/int4 are classes and are rejected).
typedef float fx4 __attribute__((ext_vector_type(4)));
typedef int   ix4 __attribute__((ext_vector_type(4)));

// One wave (64 lanes) per output row (p, o): scan T[indices[p]][o][:] for the 1.0.
// Early-exit per 1 KB chunk: branch is wave-uniform (__any), no divergence cost.
__global__ __launch_bounds__(256) void extract_perm_kernel(
        const float* __restrict__ T,
        const int* __restrict__ indices,
        int* __restrict__ perm) {
    int wave = (blockIdx.x << 2) | (threadIdx.x >> 6);  // 4 waves/block
    int lane = threadIdx.x & 63;
    int p = wave >> 10;          // output slot 0..7
    int o = wave & 1023;         // row within the permutation matrix
    int src = indices[p];        // which T block feeds output slot p
    const fx4* row = (const fx4*)(T + ((size_t)src * DIM + o) * DIM);

    int cand = -1;               // exactly one element of the row is 1.0
    #pragma unroll
    for (int k = 0; k < 4; ++k) {
        fx4 v = __builtin_nontemporal_load(row + lane + k * 64);  // coalesced 16B/lane
        int d0 = (lane + k * 64) * 4;
        if (v.x > 0.5f) cand = d0;
        if (v.y > 0.5f) cand = d0 + 1;
        if (v.z > 0.5f) cand = d0 + 2;
        if (v.w > 0.5f) cand = d0 + 3;
        if (__any(cand >= 0)) break;   // wave-uniform: the 1.0 was in this chunk
    }
    // wave-wide max reduce (losers hold -1, winner holds the index)
    #pragma unroll
    for (int off = 32; off >= 1; off >>= 1)
        cand = max(cand, __shfl_xor(cand, off));
    if (lane == 0) perm[p * DIM + o] = cand;
}

// One block per TB batch rows: indices in registers, x rows in LDS,
// coalesced float4 nontemporal stores (16 KB contiguous per p-slot).
__global__ __launch_bounds__(256) void permute_gather_kernel(
        const float* __restrict__ x,
        const int* __restrict__ perm,
        float* __restrict__ out) {
    __shared__ float xs[TB][DIM];
    const int b0 = blockIdx.x * TB;
    const int tid = threadIdx.x;

    // all 8 index quads -> registers (32 VGPRs), loaded once, L2-hot
    ix4 idx[NUM_P];
    #pragma unroll
    for (int p = 0; p < NUM_P; ++p)
        idx[p] = __builtin_nontemporal_load(((const ix4*)(perm + p * DIM)) + tid);

    // stage TB rows of x (coalesced float4: 16 KB total)
    #pragma unroll
    for (int r = 0; r < TB; ++r)
        ((fx4*)xs[r])[tid] = __builtin_nontemporal_load(
            ((const fx4*)(x + (size_t)(b0 + r) * DIM)) + tid);
    __syncthreads();

    #pragma unroll
    for (int p = 0; p < NUM_P; ++p) {
        #pragma unroll
        for (int r = 0; r < TB; ++r) {
            fx4 v;
            v.x = xs[r][idx[p].x];
            v.y = xs[r][idx[p].y];
            v.z = xs[r][idx[p].z];
            v.w = xs[r][idx[p].w];
            __builtin_nontemporal_store(
                v, (fx4*)(out + ((size_t)(p * BATCH + b0 + r)) * DIM) + tid);
        }
    }
}

extern "C" void kernel_launch(void* const* d_in, const int* in_sizes, int n_in,
                              void* d_out, int out_size, void* d_ws, size_t ws_size,
                              hipStream_t stream) {
    const float* x       = (const float*)d_in[0];
    const float* T       = (const float*)d_in[1];
    const int*   indices = (const int*)d_in[2];
    float*       out     = (float*)d_out;
    int*         perm    = (int*)d_ws;   // 8*1024*4 = 32 KB scratch

    // 8192 rows, one wave each, 4 waves per 256-thread block -> 2048 blocks
    extract_perm_kernel<<<(NUM_P * DIM) / 4, 256, 0, stream>>>(T, indices, perm);
    // 4096/TB = 1024 blocks, each writes 8 x 16 KB contiguous chunks
    permute_gather_kernel<<<BATCH / TB, 256, 0, stream>>>(x, perm, out);
}